// Round 14
// baseline (51.962 us; speedup 1.0000x reference)
//
#include <hip/hip_runtime.h>

// VIN forward — R14: timed A/B to split VI vs MLP without rocprof.
// Production pipeline BIT-IDENTICAL to R13 (dur 29.7us). Appended: 3 duplicate
// MLP dispatches into dead scratch -> MLP_us = (dur_R14 - 29.7)/3 from the
// timed path itself (immune to rocprof inflation / cache-warming artifacts).
// VI then = 29.7 - MLP - ovh.

#define K_ITERS 10

// lane i <- lane i-1 (column l-1), lane 0 <- 0.0f  (wave_shr:1, bound_ctrl:1)
__device__ __forceinline__ float shr1(float x) {
    return __int_as_float(__builtin_amdgcn_mov_dpp(__float_as_int(x), 0x138, 0xF, 0xF, true));
}
// lane i <- lane i+1 (column l+1), lane 63 <- 0.0f  (wave_shl:1, bound_ctrl:1)
__device__ __forceinline__ float shl1(float x) {
    return __int_as_float(__builtin_amdgcn_mov_dpp(__float_as_int(x), 0x130, 0xF, 0xF, true));
}
// max3-friendly: fmaxf(fmaxf(a,b),c) -> v_max3_f32
__device__ __forceinline__ float max3(float a, float b, float c) {
    return fmaxf(fmaxf(a, b), c);
}

__global__ __launch_bounds__(512) void vin_vi_kernel(
    const float* __restrict__ obs,     // [B,64,64,3]
    const float* __restrict__ W_phi,   // [3,3]
    const float* __restrict__ b_phi,   // [3]
    float* __restrict__ feats_out)     // [B,36]
{
    const int b   = blockIdx.x;
    const int tid = threadIdx.x;
    const int w   = tid >> 6;   // wave id 0..7: rows 8w .. 8w+7
    const int l   = tid & 63;   // lane = column

    __shared__ float v_s[64 * 64];     // 16 KB: final value map (gather only)
    __shared__ float bndU[2][9][64];   // v[7] of wave w-1 at [w]; [0]=0
    __shared__ float bndD[2][9][64];   // v[0] of wave w+1 at [w+1]; [8]=0
    __shared__ float rbU[9][64];       // rin row 8w-1 at [w]; [0]=0
    __shared__ float rbD[9][64];       // rin row 8w+8 at [w+1]; [8]=0
    __shared__ int   agent_pos;

    const float* ob = obs + (size_t)b * (4096 * 3);

    const float w00 = W_phi[0], w01 = W_phi[1], w02 = W_phi[2];
    const float w10 = W_phi[3], w11 = W_phi[4], w12 = W_phi[5];
    const float w20 = W_phi[6], w21 = W_phi[7], w22 = W_phi[8];
    const float bp0 = b_phi[0], bp1 = b_phi[1], bp2 = b_phi[2];

    // Load + phi for the 8 owned rows.
    float pk[8], rik[8], rok[8];
    #pragma unroll
    for (int k = 0; k < 8; ++k) {
        const int cell = (8 * w + k) * 64 + l;
        const float o0 = ob[cell * 3 + 0];
        const float o1 = ob[cell * 3 + 1];
        const float o2 = ob[cell * 3 + 2];
        pk[k]  = fmaxf(fmaf(o2, w20, fmaf(o1, w10, fmaf(o0, w00, bp0))), 0.f);
        rik[k] = fmaxf(fmaf(o2, w21, fmaf(o1, w11, fmaf(o0, w01, bp1))), 0.f);
        rok[k] = fmaxf(fmaf(o2, w22, fmaf(o1, w12, fmaf(o0, w02, bp2))), 0.f);
        if (o1 > 0.5f) agent_pos = cell;   // one-hot agent: single writer
    }
    const float p0 = pk[0], p1 = pk[1], p2 = pk[2], p3 = pk[3];
    const float p4 = pk[4], p5 = pk[5], p6 = pk[6], p7 = pk[7];

    // Zero pad rows (written once) + static rin boundary rows.
    if (tid < 64) {
        bndU[0][0][l] = 0.f; bndU[1][0][l] = 0.f;
        bndD[0][8][l] = 0.f; bndD[1][8][l] = 0.f;
        rbU[0][l] = 0.f;     rbD[8][l] = 0.f;
    }
    rbU[w + 1][l] = rik[7];   // rin of my last row, for wave w+1's "up"
    rbD[w][l]     = rik[0];   // rin of my first row, for wave w-1's "down"
    __syncthreads();
    const float rinU_b = rbU[w][l];
    const float rinD_b = rbD[w + 1][l];

    // Folded per-direction constants aX = rin(neighbor X) - rout.
    // Out-of-grid terms = -rout <= 0 never win (v>=0 monotone, relu >= 0,
    // DPP zero-fill at wave edges, zero pad rows vertically).
    const float aU0 = rinU_b - rok[0], aU1 = rik[0] - rok[1], aU2 = rik[1] - rok[2], aU3 = rik[2] - rok[3];
    const float aU4 = rik[3] - rok[4], aU5 = rik[4] - rok[5], aU6 = rik[5] - rok[6], aU7 = rik[6] - rok[7];
    const float aD0 = rik[1] - rok[0], aD1 = rik[2] - rok[1], aD2 = rik[3] - rok[2], aD3 = rik[4] - rok[3];
    const float aD4 = rik[5] - rok[4], aD5 = rik[6] - rok[5], aD6 = rik[7] - rok[6], aD7 = rinD_b - rok[7];
    const float aL0 = shr1(rik[0]) - rok[0], aL1 = shr1(rik[1]) - rok[1], aL2 = shr1(rik[2]) - rok[2], aL3 = shr1(rik[3]) - rok[3];
    const float aL4 = shr1(rik[4]) - rok[4], aL5 = shr1(rik[5]) - rok[5], aL6 = shr1(rik[6]) - rok[6], aL7 = shr1(rik[7]) - rok[7];
    const float aR0 = shl1(rik[0]) - rok[0], aR1 = shl1(rik[1]) - rok[1], aR2 = shl1(rik[2]) - rok[2], aR3 = shl1(rik[3]) - rok[3];
    const float aR4 = shl1(rik[4]) - rok[4], aR5 = shl1(rik[5]) - rok[5], aR6 = shl1(rik[6]) - rok[6], aR7 = shl1(rik[7]) - rok[7];

    // Iter 0 peeled (v == 0): v = max(0, aU, aD, aL, aR).
    float v0 = fmaxf(max3(aU0, aD0, aL0), fmaxf(aR0, 0.f));
    float v1 = fmaxf(max3(aU1, aD1, aL1), fmaxf(aR1, 0.f));
    float v2 = fmaxf(max3(aU2, aD2, aL2), fmaxf(aR2, 0.f));
    float v3 = fmaxf(max3(aU3, aD3, aL3), fmaxf(aR3, 0.f));
    float v4 = fmaxf(max3(aU4, aD4, aL4), fmaxf(aR4, 0.f));
    float v5 = fmaxf(max3(aU5, aD5, aL5), fmaxf(aR5, 0.f));
    float v6 = fmaxf(max3(aU6, aD6, aL6), fmaxf(aR6, 0.f));
    float v7 = fmaxf(max3(aU7, aD7, aL7), fmaxf(aR7, 0.f));
    bndU[0][w + 1][l] = v7;
    bndD[0][w][l]     = v0;

    // Iters 1..9, fully unrolled; Jacobi via SSA names (all reads of old v).
    #pragma unroll
    for (int it = 1; it < K_ITERS; ++it) {
        const int rd = (it - 1) & 1, wr = it & 1;
        __syncthreads();
        const float vU_b = bndU[rd][w][l];
        const float vD_b = bndD[rd][w + 1][l];

        float vL, vR, m;
        vL = shr1(v7); vR = shl1(v7);
        m = max3(fmaf(p7, v6, aU7), fmaf(p7, vD_b, aD7), fmaf(p7, vL, aL7));
        const float nv7 = max3(m, fmaf(p7, vR, aR7), v7);
        bndU[wr][w + 1][l] = nv7;

        vL = shr1(v0); vR = shl1(v0);
        m = max3(fmaf(p0, vU_b, aU0), fmaf(p0, v1, aD0), fmaf(p0, vL, aL0));
        const float nv0 = max3(m, fmaf(p0, vR, aR0), v0);
        bndD[wr][w][l] = nv0;

        vL = shr1(v1); vR = shl1(v1);
        m = max3(fmaf(p1, v0, aU1), fmaf(p1, v2, aD1), fmaf(p1, vL, aL1));
        const float nv1 = max3(m, fmaf(p1, vR, aR1), v1);

        vL = shr1(v2); vR = shl1(v2);
        m = max3(fmaf(p2, v1, aU2), fmaf(p2, v3, aD2), fmaf(p2, vL, aL2));
        const float nv2 = max3(m, fmaf(p2, vR, aR2), v2);

        vL = shr1(v3); vR = shl1(v3);
        m = max3(fmaf(p3, v2, aU3), fmaf(p3, v4, aD3), fmaf(p3, vL, aL3));
        const float nv3 = max3(m, fmaf(p3, vR, aR3), v3);

        vL = shr1(v4); vR = shl1(v4);
        m = max3(fmaf(p4, v3, aU4), fmaf(p4, v5, aD4), fmaf(p4, vL, aL4));
        const float nv4 = max3(m, fmaf(p4, vR, aR4), v4);

        vL = shr1(v5); vR = shl1(v5);
        m = max3(fmaf(p5, v4, aU5), fmaf(p5, v6, aD5), fmaf(p5, vL, aL5));
        const float nv5 = max3(m, fmaf(p5, vR, aR5), v5);

        vL = shr1(v6); vR = shl1(v6);
        m = max3(fmaf(p6, v5, aU6), fmaf(p6, v7, aD6), fmaf(p6, vL, aL6));
        const float nv6 = max3(m, fmaf(p6, vR, aR6), v6);

        v0 = nv0; v1 = nv1; v2 = nv2; v3 = nv3;
        v4 = nv4; v5 = nv5; v6 = nv6; v7 = nv7;
    }

    v_s[(8 * w + 0) * 64 + l] = v0;
    v_s[(8 * w + 1) * 64 + l] = v1;
    v_s[(8 * w + 2) * 64 + l] = v2;
    v_s[(8 * w + 3) * 64 + l] = v3;
    v_s[(8 * w + 4) * 64 + l] = v4;
    v_s[(8 * w + 5) * 64 + l] = v5;
    v_s[(8 * w + 6) * 64 + l] = v6;
    v_s[(8 * w + 7) * 64 + l] = v7;
    __syncthreads();

    // 36 features: 3x3 zero-padded windows of (1-walls), agent, goal, v.
    if (tid < 36) {
        const int ap = agent_pos;
        const int ar = ap >> 6, ac = ap & 63;
        const int g  = tid / 9, o = tid % 9;
        const int rr = ar + o / 3 - 1;
        const int cc = ac + o % 3 - 1;
        float val = 0.f;
        if (rr >= 0 && rr < 64 && cc >= 0 && cc < 64) {
            const int cell = rr * 64 + cc;
            if      (g == 0) val = 1.f - ob[cell * 3 + 0];
            else if (g == 1) val = ob[cell * 3 + 1];
            else if (g == 2) val = ob[cell * 3 + 2];
            else             val = v_s[cell];
        }
        feats_out[b * 36 + tid] = val;
    }
}

// MLP 36->256->256->5; 4 samples/block; phase-2: 8-way K-split, 2 cols/thread.
__global__ __launch_bounds__(1024) void vin_mlp_kernel(
    const float* __restrict__ feats,   // [B,36]
    const float* __restrict__ W1,      // [36,256]
    const float* __restrict__ b1,      // [256]
    const float* __restrict__ W2,      // [256,256]
    const float* __restrict__ b2,      // [256]
    const float* __restrict__ Wl,      // [256,5]
    const float* __restrict__ bl,      // [5]
    float* __restrict__ out)           // [B,5]
{
    const int b0  = blockIdx.x * 4;    // 4 samples per block
    const int tid = threadIdx.x;

    __shared__ float f_s[4][36];
    __shared__ __align__(16) float part[8][4][256]; // [octant][sample][col] 32KB
    __shared__ __align__(16) float h1_s[256][4];    // [col][sample] 4KB
    __shared__ float h2_s[4][256];                  // 4KB
    __shared__ float red[16][4][5];                 // 1.25KB

    if (tid < 144) f_s[tid / 36][tid % 36] = feats[b0 * 36 + tid];
    __syncthreads();

    // 36 -> 256 (linear), 4-way K-split: quarter q4 sums rows [9q4, 9q4+9)
    {
        const int q4 = tid >> 8;       // 0..3
        const int c  = tid & 255;
        float a0 = 0.f, a1 = 0.f, a2 = 0.f, a3 = 0.f;
        #pragma unroll
        for (int m = 0; m < 9; ++m) {
            const int i = 9 * q4 + m;
            const float wv = W1[i * 256 + c];
            a0 = fmaf(f_s[0][i], wv, a0);
            a1 = fmaf(f_s[1][i], wv, a1);
            a2 = fmaf(f_s[2][i], wv, a2);
            a3 = fmaf(f_s[3][i], wv, a3);
        }
        part[q4][0][c] = a0; part[q4][1][c] = a1;
        part[q4][2][c] = a2; part[q4][3][c] = a3;
    }
    __syncthreads();
    {
        const int q4 = tid >> 8, c = tid & 255;
        h1_s[c][q4] = b1[c] + ((part[0][q4][c] + part[1][q4][c]) +
                               (part[2][q4][c] + part[3][q4][c]));
    }
    __syncthreads();

    // 256 -> 256 (linear), 8-way K-split, 2 cols/thread: one float4 h1
    // broadcast feeds 8 FMAs -> LDS-pipe instrs halve vs 1 col/thread.
    {
        const int q  = tid >> 7;       // K-octant: rows [32q, 32q+32)
        const int cp = tid & 127;      // columns 2cp, 2cp+1
        float a00 = 0.f, a01 = 0.f, a10 = 0.f, a11 = 0.f;
        float a20 = 0.f, a21 = 0.f, a30 = 0.f, a31 = 0.f;
        #pragma unroll
        for (int m = 0; m < 32; ++m) {
            const int i = 32 * q + m;
            const float2 wv = *reinterpret_cast<const float2*>(&W2[i * 256 + 2 * cp]);
            const float4 hv = *reinterpret_cast<const float4*>(&h1_s[i][0]); // bcast
            a00 = fmaf(hv.x, wv.x, a00); a01 = fmaf(hv.x, wv.y, a01);
            a10 = fmaf(hv.y, wv.x, a10); a11 = fmaf(hv.y, wv.y, a11);
            a20 = fmaf(hv.z, wv.x, a20); a21 = fmaf(hv.z, wv.y, a21);
            a30 = fmaf(hv.w, wv.x, a30); a31 = fmaf(hv.w, wv.y, a31);
        }
        *reinterpret_cast<float2*>(&part[q][0][2 * cp]) = make_float2(a00, a01);
        *reinterpret_cast<float2*>(&part[q][1][2 * cp]) = make_float2(a10, a11);
        *reinterpret_cast<float2*>(&part[q][2][2 * cp]) = make_float2(a20, a21);
        *reinterpret_cast<float2*>(&part[q][3][2 * cp]) = make_float2(a30, a31);
    }
    __syncthreads();
    {
        const int q4 = tid >> 8, c = tid & 255;
        float t = b2[c];
        #pragma unroll
        for (int qq = 0; qq < 8; ++qq) t += part[qq][q4][c];
        h2_s[q4][c] = t;
    }
    __syncthreads();

    // 256 -> 5: 320 threads, each sums a 16-wide chunk for one (sample,logit)
    if (tid < 320) {
        const int s  = tid & 3;
        const int j  = (tid >> 2) % 5;
        const int ch = tid / 20;        // 0..15
        float acc = 0.f;
        #pragma unroll
        for (int m = 0; m < 16; ++m) {
            const int i = ch * 16 + m;
            acc = fmaf(h2_s[s][i], Wl[i * 5 + j], acc);
        }
        red[ch][s][j] = acc;
    }
    __syncthreads();
    if (tid < 20) {
        const int s = tid & 3;
        const int j = tid >> 2;
        float o = bl[j];
        #pragma unroll
        for (int ch = 0; ch < 16; ++ch) o += red[ch][s][j];
        out[(b0 + s) * 5 + j] = o;
    }
}

extern "C" void kernel_launch(void* const* d_in, const int* in_sizes, int n_in,
                              void* d_out, int out_size, void* d_ws, size_t ws_size,
                              hipStream_t stream) {
    const float* obs   = (const float*)d_in[0];
    const float* W_phi = (const float*)d_in[1];
    const float* b_phi = (const float*)d_in[2];
    const float* W1    = (const float*)d_in[3];
    const float* b1    = (const float*)d_in[4];
    const float* W2    = (const float*)d_in[5];
    const float* b2    = (const float*)d_in[6];
    const float* Wl    = (const float*)d_in[7];
    const float* bl    = (const float*)d_in[8];
    float* out   = (float*)d_out;
    float* feats = (float*)d_ws;   // 1024*36*4 = 147456 bytes

    // Production (bit-identical to R13).
    vin_vi_kernel<<<dim3(1024), dim3(512), 0, stream>>>(obs, W_phi, b_phi, feats);
    vin_mlp_kernel<<<dim3(256), dim3(1024), 0, stream>>>(feats, W1, b1, W2, b2, Wl, bl, out);

    // Timed A/B instrument: 3 duplicate MLP dispatches into dead scratch.
    // MLP_us = (dur_R14 - dur_R13) / 3, measured by the harness timer itself.
    if (ws_size >= (8u << 20)) {
        float* dg = (float*)((char*)d_ws + (4u << 20));   // 3 x 5120 floats
        vin_mlp_kernel<<<dim3(256), dim3(1024), 0, stream>>>(feats, W1, b1, W2, b2, Wl, bl, dg);
        vin_mlp_kernel<<<dim3(256), dim3(1024), 0, stream>>>(feats, W1, b1, W2, b2, Wl, bl, dg + 8192);
        vin_mlp_kernel<<<dim3(256), dim3(1024), 0, stream>>>(feats, W1, b1, W2, b2, Wl, bl, dg + 16384);
    }
}

// Round 15
// 29.073 us; speedup vs baseline: 1.7873x; 1.7873x over previous
//
#include <hip/hip_runtime.h>

// VIN forward — R15: fix the VI obs-load bandwidth.
// R14 A/B: MLP = 7.4us, VI+ovh = 22.3us. R12 replica showed the VI obs path
// streams at only ~2 TB/s: 24 scalar dword loads/thread at stride-12B scatter
// each instruction over 12 cache lines, and the harness's 268MB fill resets
// make obs HBM-cold every replay -> VI is load-BW-bound (50MB @ 2.2TB/s = 22us).
// Fix: stage the 48KB obs tile into LDS with 6 contiguous float4 loads/thread
// (1KB/wave-instr, fully coalesced), read cells from LDS. v_s aliases the
// staging buffer (dead after phi). LDS 63KB -> 2 blocks/CU.

#define K_ITERS 10

// lane i <- lane i-1 (column l-1), lane 0 <- 0.0f  (wave_shr:1, bound_ctrl:1)
__device__ __forceinline__ float shr1(float x) {
    return __int_as_float(__builtin_amdgcn_mov_dpp(__float_as_int(x), 0x138, 0xF, 0xF, true));
}
// lane i <- lane i+1 (column l+1), lane 63 <- 0.0f  (wave_shl:1, bound_ctrl:1)
__device__ __forceinline__ float shl1(float x) {
    return __int_as_float(__builtin_amdgcn_mov_dpp(__float_as_int(x), 0x130, 0xF, 0xF, true));
}
// max3-friendly: fmaxf(fmaxf(a,b),c) -> v_max3_f32
__device__ __forceinline__ float max3(float a, float b, float c) {
    return fmaxf(fmaxf(a, b), c);
}

__global__ __launch_bounds__(512) void vin_vi_kernel(
    const float* __restrict__ obs,     // [B,64,64,3]
    const float* __restrict__ W_phi,   // [3,3]
    const float* __restrict__ b_phi,   // [3]
    float* __restrict__ feats_out)     // [B,36]
{
    const int b   = blockIdx.x;
    const int tid = threadIdx.x;
    const int w   = tid >> 6;   // wave id 0..7: rows 8w .. 8w+7
    const int l   = tid & 63;   // lane = column

    // 48KB staging tile for obs[b] (12288 floats). After phi consumes it,
    // the first 4096 floats are reused as the final value map v_s.
    __shared__ __align__(16) float stage_s[12288];
    __shared__ float bndU[2][9][64];   // v[7] of wave w-1 at [w]; [0]=0
    __shared__ float bndD[2][9][64];   // v[0] of wave w+1 at [w+1]; [8]=0
    __shared__ float rbU[9][64];       // rin row 8w-1 at [w]; [0]=0
    __shared__ float rbD[9][64];       // rin row 8w+8 at [w+1]; [8]=0
    __shared__ int   agent_pos;
    float* v_s = stage_s;              // alias (stage dead after phi)

    const float* ob = obs + (size_t)b * (4096 * 3);

    // ---- Stage obs tile: 6 x float4 per thread, lane-contiguous (1KB/wave) ----
    {
        const float4* ob4 = reinterpret_cast<const float4*>(ob);
        float4* st4 = reinterpret_cast<float4*>(stage_s);
        #pragma unroll
        for (int i = 0; i < 6; ++i)
            st4[i * 512 + tid] = ob4[i * 512 + tid];
    }
    // Zero pad rows (independent LDS, written once).
    if (tid < 64) {
        bndU[0][0][l] = 0.f; bndU[1][0][l] = 0.f;
        bndD[0][8][l] = 0.f; bndD[1][8][l] = 0.f;
        rbU[0][l] = 0.f;     rbD[8][l] = 0.f;
    }
    __syncthreads();

    const float w00 = W_phi[0], w01 = W_phi[1], w02 = W_phi[2];
    const float w10 = W_phi[3], w11 = W_phi[4], w12 = W_phi[5];
    const float w20 = W_phi[6], w21 = W_phi[7], w22 = W_phi[8];
    const float bp0 = b_phi[0], bp1 = b_phi[1], bp2 = b_phi[2];

    // ---- phi for the 8 owned rows, read from LDS ----
    float pk[8], rik[8], rok[8];
    #pragma unroll
    for (int k = 0; k < 8; ++k) {
        const int cell = (8 * w + k) * 64 + l;
        const float o0 = stage_s[cell * 3 + 0];
        const float o1 = stage_s[cell * 3 + 1];
        const float o2 = stage_s[cell * 3 + 2];
        pk[k]  = fmaxf(fmaf(o2, w20, fmaf(o1, w10, fmaf(o0, w00, bp0))), 0.f);
        rik[k] = fmaxf(fmaf(o2, w21, fmaf(o1, w11, fmaf(o0, w01, bp1))), 0.f);
        rok[k] = fmaxf(fmaf(o2, w22, fmaf(o1, w12, fmaf(o0, w02, bp2))), 0.f);
        if (o1 > 0.5f) agent_pos = cell;   // one-hot agent: single writer
    }
    const float p0 = pk[0], p1 = pk[1], p2 = pk[2], p3 = pk[3];
    const float p4 = pk[4], p5 = pk[5], p6 = pk[6], p7 = pk[7];

    // Static rin boundary rows.
    rbU[w + 1][l] = rik[7];   // rin of my last row, for wave w+1's "up"
    rbD[w][l]     = rik[0];   // rin of my first row, for wave w-1's "down"
    __syncthreads();
    const float rinU_b = rbU[w][l];
    const float rinD_b = rbD[w + 1][l];

    // Folded per-direction constants aX = rin(neighbor X) - rout.
    // Out-of-grid terms = -rout <= 0 never win (v>=0 monotone, relu >= 0,
    // DPP zero-fill at wave edges, zero pad rows vertically).
    const float aU0 = rinU_b - rok[0], aU1 = rik[0] - rok[1], aU2 = rik[1] - rok[2], aU3 = rik[2] - rok[3];
    const float aU4 = rik[3] - rok[4], aU5 = rik[4] - rok[5], aU6 = rik[5] - rok[6], aU7 = rik[6] - rok[7];
    const float aD0 = rik[1] - rok[0], aD1 = rik[2] - rok[1], aD2 = rik[3] - rok[2], aD3 = rik[4] - rok[3];
    const float aD4 = rik[5] - rok[4], aD5 = rik[6] - rok[5], aD6 = rik[7] - rok[6], aD7 = rinD_b - rok[7];
    const float aL0 = shr1(rik[0]) - rok[0], aL1 = shr1(rik[1]) - rok[1], aL2 = shr1(rik[2]) - rok[2], aL3 = shr1(rik[3]) - rok[3];
    const float aL4 = shr1(rik[4]) - rok[4], aL5 = shr1(rik[5]) - rok[5], aL6 = shr1(rik[6]) - rok[6], aL7 = shr1(rik[7]) - rok[7];
    const float aR0 = shl1(rik[0]) - rok[0], aR1 = shl1(rik[1]) - rok[1], aR2 = shl1(rik[2]) - rok[2], aR3 = shl1(rik[3]) - rok[3];
    const float aR4 = shl1(rik[4]) - rok[4], aR5 = shl1(rik[5]) - rok[5], aR6 = shl1(rik[6]) - rok[6], aR7 = shl1(rik[7]) - rok[7];

    // Iter 0 peeled (v == 0): v = max(0, aU, aD, aL, aR).
    float v0 = fmaxf(max3(aU0, aD0, aL0), fmaxf(aR0, 0.f));
    float v1 = fmaxf(max3(aU1, aD1, aL1), fmaxf(aR1, 0.f));
    float v2 = fmaxf(max3(aU2, aD2, aL2), fmaxf(aR2, 0.f));
    float v3 = fmaxf(max3(aU3, aD3, aL3), fmaxf(aR3, 0.f));
    float v4 = fmaxf(max3(aU4, aD4, aL4), fmaxf(aR4, 0.f));
    float v5 = fmaxf(max3(aU5, aD5, aL5), fmaxf(aR5, 0.f));
    float v6 = fmaxf(max3(aU6, aD6, aL6), fmaxf(aR6, 0.f));
    float v7 = fmaxf(max3(aU7, aD7, aL7), fmaxf(aR7, 0.f));
    bndU[0][w + 1][l] = v7;
    bndD[0][w][l]     = v0;

    // Iters 1..9, fully unrolled; Jacobi via SSA names (all reads of old v).
    #pragma unroll
    for (int it = 1; it < K_ITERS; ++it) {
        const int rd = (it - 1) & 1, wr = it & 1;
        __syncthreads();
        const float vU_b = bndU[rd][w][l];
        const float vD_b = bndD[rd][w + 1][l];

        float vL, vR, m;
        vL = shr1(v7); vR = shl1(v7);
        m = max3(fmaf(p7, v6, aU7), fmaf(p7, vD_b, aD7), fmaf(p7, vL, aL7));
        const float nv7 = max3(m, fmaf(p7, vR, aR7), v7);
        bndU[wr][w + 1][l] = nv7;

        vL = shr1(v0); vR = shl1(v0);
        m = max3(fmaf(p0, vU_b, aU0), fmaf(p0, v1, aD0), fmaf(p0, vL, aL0));
        const float nv0 = max3(m, fmaf(p0, vR, aR0), v0);
        bndD[wr][w][l] = nv0;

        vL = shr1(v1); vR = shl1(v1);
        m = max3(fmaf(p1, v0, aU1), fmaf(p1, v2, aD1), fmaf(p1, vL, aL1));
        const float nv1 = max3(m, fmaf(p1, vR, aR1), v1);

        vL = shr1(v2); vR = shl1(v2);
        m = max3(fmaf(p2, v1, aU2), fmaf(p2, v3, aD2), fmaf(p2, vL, aL2));
        const float nv2 = max3(m, fmaf(p2, vR, aR2), v2);

        vL = shr1(v3); vR = shl1(v3);
        m = max3(fmaf(p3, v2, aU3), fmaf(p3, v4, aD3), fmaf(p3, vL, aL3));
        const float nv3 = max3(m, fmaf(p3, vR, aR3), v3);

        vL = shr1(v4); vR = shl1(v4);
        m = max3(fmaf(p4, v3, aU4), fmaf(p4, v5, aD4), fmaf(p4, vL, aL4));
        const float nv4 = max3(m, fmaf(p4, vR, aR4), v4);

        vL = shr1(v5); vR = shl1(v5);
        m = max3(fmaf(p5, v4, aU5), fmaf(p5, v6, aD5), fmaf(p5, vL, aL5));
        const float nv5 = max3(m, fmaf(p5, vR, aR5), v5);

        vL = shr1(v6); vR = shl1(v6);
        m = max3(fmaf(p6, v5, aU6), fmaf(p6, v7, aD6), fmaf(p6, vL, aL6));
        const float nv6 = max3(m, fmaf(p6, vR, aR6), v6);

        v0 = nv0; v1 = nv1; v2 = nv2; v3 = nv3;
        v4 = nv4; v5 = nv5; v6 = nv6; v7 = nv7;
    }
    __syncthreads();   // all phi reads of stage_s done long ago; reuse as v_s

    v_s[(8 * w + 0) * 64 + l] = v0;
    v_s[(8 * w + 1) * 64 + l] = v1;
    v_s[(8 * w + 2) * 64 + l] = v2;
    v_s[(8 * w + 3) * 64 + l] = v3;
    v_s[(8 * w + 4) * 64 + l] = v4;
    v_s[(8 * w + 5) * 64 + l] = v5;
    v_s[(8 * w + 6) * 64 + l] = v6;
    v_s[(8 * w + 7) * 64 + l] = v7;
    __syncthreads();

    // 36 features: 3x3 zero-padded windows of (1-walls), agent, goal, v.
    // walls/agent/goal re-read from global (36 scattered dwords, L2-warm).
    if (tid < 36) {
        const int ap = agent_pos;
        const int ar = ap >> 6, ac = ap & 63;
        const int g  = tid / 9, o = tid % 9;
        const int rr = ar + o / 3 - 1;
        const int cc = ac + o % 3 - 1;
        float val = 0.f;
        if (rr >= 0 && rr < 64 && cc >= 0 && cc < 64) {
            const int cell = rr * 64 + cc;
            if      (g == 0) val = 1.f - ob[cell * 3 + 0];
            else if (g == 1) val = ob[cell * 3 + 1];
            else if (g == 2) val = ob[cell * 3 + 2];
            else             val = v_s[cell];
        }
        feats_out[b * 36 + tid] = val;
    }
}

// MLP 36->256->256->5; 4 samples/block; phase-2: 8-way K-split, 2 cols/thread.
__global__ __launch_bounds__(1024) void vin_mlp_kernel(
    const float* __restrict__ feats,   // [B,36]
    const float* __restrict__ W1,      // [36,256]
    const float* __restrict__ b1,      // [256]
    const float* __restrict__ W2,      // [256,256]
    const float* __restrict__ b2,      // [256]
    const float* __restrict__ Wl,      // [256,5]
    const float* __restrict__ bl,      // [5]
    float* __restrict__ out)           // [B,5]
{
    const int b0  = blockIdx.x * 4;    // 4 samples per block
    const int tid = threadIdx.x;

    __shared__ float f_s[4][36];
    __shared__ __align__(16) float part[8][4][256]; // [octant][sample][col] 32KB
    __shared__ __align__(16) float h1_s[256][4];    // [col][sample] 4KB
    __shared__ float h2_s[4][256];                  // 4KB
    __shared__ float red[16][4][5];                 // 1.25KB

    if (tid < 144) f_s[tid / 36][tid % 36] = feats[b0 * 36 + tid];
    __syncthreads();

    // 36 -> 256 (linear), 4-way K-split: quarter q4 sums rows [9q4, 9q4+9)
    {
        const int q4 = tid >> 8;       // 0..3
        const int c  = tid & 255;
        float a0 = 0.f, a1 = 0.f, a2 = 0.f, a3 = 0.f;
        #pragma unroll
        for (int m = 0; m < 9; ++m) {
            const int i = 9 * q4 + m;
            const float wv = W1[i * 256 + c];
            a0 = fmaf(f_s[0][i], wv, a0);
            a1 = fmaf(f_s[1][i], wv, a1);
            a2 = fmaf(f_s[2][i], wv, a2);
            a3 = fmaf(f_s[3][i], wv, a3);
        }
        part[q4][0][c] = a0; part[q4][1][c] = a1;
        part[q4][2][c] = a2; part[q4][3][c] = a3;
    }
    __syncthreads();
    {
        const int q4 = tid >> 8, c = tid & 255;
        h1_s[c][q4] = b1[c] + ((part[0][q4][c] + part[1][q4][c]) +
                               (part[2][q4][c] + part[3][q4][c]));
    }
    __syncthreads();

    // 256 -> 256 (linear), 8-way K-split, 2 cols/thread: one float4 h1
    // broadcast feeds 8 FMAs.
    {
        const int q  = tid >> 7;       // K-octant: rows [32q, 32q+32)
        const int cp = tid & 127;      // columns 2cp, 2cp+1
        float a00 = 0.f, a01 = 0.f, a10 = 0.f, a11 = 0.f;
        float a20 = 0.f, a21 = 0.f, a30 = 0.f, a31 = 0.f;
        #pragma unroll
        for (int m = 0; m < 32; ++m) {
            const int i = 32 * q + m;
            const float2 wv = *reinterpret_cast<const float2*>(&W2[i * 256 + 2 * cp]);
            const float4 hv = *reinterpret_cast<const float4*>(&h1_s[i][0]); // bcast
            a00 = fmaf(hv.x, wv.x, a00); a01 = fmaf(hv.x, wv.y, a01);
            a10 = fmaf(hv.y, wv.x, a10); a11 = fmaf(hv.y, wv.y, a11);
            a20 = fmaf(hv.z, wv.x, a20); a21 = fmaf(hv.z, wv.y, a21);
            a30 = fmaf(hv.w, wv.x, a30); a31 = fmaf(hv.w, wv.y, a31);
        }
        *reinterpret_cast<float2*>(&part[q][0][2 * cp]) = make_float2(a00, a01);
        *reinterpret_cast<float2*>(&part[q][1][2 * cp]) = make_float2(a10, a11);
        *reinterpret_cast<float2*>(&part[q][2][2 * cp]) = make_float2(a20, a21);
        *reinterpret_cast<float2*>(&part[q][3][2 * cp]) = make_float2(a30, a31);
    }
    __syncthreads();
    {
        const int q4 = tid >> 8, c = tid & 255;
        float t = b2[c];
        #pragma unroll
        for (int qq = 0; qq < 8; ++qq) t += part[qq][q4][c];
        h2_s[q4][c] = t;
    }
    __syncthreads();

    // 256 -> 5: 320 threads, each sums a 16-wide chunk for one (sample,logit)
    if (tid < 320) {
        const int s  = tid & 3;
        const int j  = (tid >> 2) % 5;
        const int ch = tid / 20;        // 0..15
        float acc = 0.f;
        #pragma unroll
        for (int m = 0; m < 16; ++m) {
            const int i = ch * 16 + m;
            acc = fmaf(h2_s[s][i], Wl[i * 5 + j], acc);
        }
        red[ch][s][j] = acc;
    }
    __syncthreads();
    if (tid < 20) {
        const int s = tid & 3;
        const int j = tid >> 2;
        float o = bl[j];
        #pragma unroll
        for (int ch = 0; ch < 16; ++ch) o += red[ch][s][j];
        out[(b0 + s) * 5 + j] = o;
    }
}

extern "C" void kernel_launch(void* const* d_in, const int* in_sizes, int n_in,
                              void* d_out, int out_size, void* d_ws, size_t ws_size,
                              hipStream_t stream) {
    const float* obs   = (const float*)d_in[0];
    const float* W_phi = (const float*)d_in[1];
    const float* b_phi = (const float*)d_in[2];
    const float* W1    = (const float*)d_in[3];
    const float* b1    = (const float*)d_in[4];
    const float* W2    = (const float*)d_in[5];
    const float* b2    = (const float*)d_in[6];
    const float* Wl    = (const float*)d_in[7];
    const float* bl    = (const float*)d_in[8];
    float* out   = (float*)d_out;
    float* feats = (float*)d_ws;   // 1024*36*4 = 147456 bytes

    vin_vi_kernel<<<dim3(1024), dim3(512), 0, stream>>>(obs, W_phi, b_phi, feats);
    vin_mlp_kernel<<<dim3(256), dim3(1024), 0, stream>>>(feats, W1, b1, W2, b2, Wl, bl, out);
}

// Round 16
// 28.459 us; speedup vs baseline: 1.8258x; 1.0216x over previous
//
#include <hip/hip_runtime.h>

// VIN forward — R16: single fused kernel (VI + gather + MLP).
// R15 null: coalesced obs staging = no change -> VI isn't load-pattern-bound.
// Recalibrated budget says the ~8us residual is phase serialization + the
// 2nd-kernel launch gap. Fuse: grid 1024 x 512thr; per block: VI for sample b
// (R13 direct loads, ~34KB LDS -> 4 blocks/CU), in-LDS gather of the 36
// features, then a 1-sample MLP (2-way K-split) writing out[b*5..] directly.
// MLP work overlaps other blocks' obs streams; no feats round-trip; W2 stays
// L2-resident (256KB/XCD).

#define K_ITERS 10

// lane i <- lane i-1 (column l-1), lane 0 <- 0.0f  (wave_shr:1, bound_ctrl:1)
__device__ __forceinline__ float shr1(float x) {
    return __int_as_float(__builtin_amdgcn_mov_dpp(__float_as_int(x), 0x138, 0xF, 0xF, true));
}
// lane i <- lane i+1 (column l+1), lane 63 <- 0.0f  (wave_shl:1, bound_ctrl:1)
__device__ __forceinline__ float shl1(float x) {
    return __int_as_float(__builtin_amdgcn_mov_dpp(__float_as_int(x), 0x130, 0xF, 0xF, true));
}
// max3-friendly: fmaxf(fmaxf(a,b),c) -> v_max3_f32
__device__ __forceinline__ float max3(float a, float b, float c) {
    return fmaxf(fmaxf(a, b), c);
}

__global__ __launch_bounds__(512) void vin_fused_kernel(
    const float* __restrict__ obs,     // [B,64,64,3]
    const float* __restrict__ W_phi,   // [3,3]
    const float* __restrict__ b_phi,   // [3]
    const float* __restrict__ W1,      // [36,256]
    const float* __restrict__ b1,      // [256]
    const float* __restrict__ W2,      // [256,256]
    const float* __restrict__ b2,      // [256]
    const float* __restrict__ Wl,      // [256,5]
    const float* __restrict__ bl,      // [5]
    float* __restrict__ out)           // [B,5]
{
    const int b   = blockIdx.x;
    const int tid = threadIdx.x;
    const int w   = tid >> 6;   // wave id 0..7: rows 8w .. 8w+7
    const int l   = tid & 63;   // lane = column

    __shared__ float v_s[64 * 64];     // 16 KB: final value map (gather only)
    __shared__ float bndU[2][9][64];   // v[7] of wave w-1 at [w]; [0]=0
    __shared__ float bndD[2][9][64];   // v[0] of wave w+1 at [w+1]; [8]=0
    __shared__ float rbU[9][64];       // rin row 8w-1 at [w]; [0]=0
    __shared__ float rbD[9][64];       // rin row 8w+8 at [w+1]; [8]=0
    __shared__ int   agent_pos;
    // MLP scratch (live only after the gather):
    __shared__ float f_s[36];
    __shared__ float part_s[2][256];                 // 2 KB
    __shared__ __align__(16) float h1_s[256];        // 1 KB
    __shared__ float h2_s[256];                      // 1 KB
    __shared__ float red[8][5];

    const float* ob = obs + (size_t)b * (4096 * 3);

    const float w00 = W_phi[0], w01 = W_phi[1], w02 = W_phi[2];
    const float w10 = W_phi[3], w11 = W_phi[4], w12 = W_phi[5];
    const float w20 = W_phi[6], w21 = W_phi[7], w22 = W_phi[8];
    const float bp0 = b_phi[0], bp1 = b_phi[1], bp2 = b_phi[2];

    // ---- VI: load + phi for the 8 owned rows ----
    float pk[8], rik[8], rok[8];
    #pragma unroll
    for (int k = 0; k < 8; ++k) {
        const int cell = (8 * w + k) * 64 + l;
        const float o0 = ob[cell * 3 + 0];
        const float o1 = ob[cell * 3 + 1];
        const float o2 = ob[cell * 3 + 2];
        pk[k]  = fmaxf(fmaf(o2, w20, fmaf(o1, w10, fmaf(o0, w00, bp0))), 0.f);
        rik[k] = fmaxf(fmaf(o2, w21, fmaf(o1, w11, fmaf(o0, w01, bp1))), 0.f);
        rok[k] = fmaxf(fmaf(o2, w22, fmaf(o1, w12, fmaf(o0, w02, bp2))), 0.f);
        if (o1 > 0.5f) agent_pos = cell;   // one-hot agent: single writer
    }
    const float p0 = pk[0], p1 = pk[1], p2 = pk[2], p3 = pk[3];
    const float p4 = pk[4], p5 = pk[5], p6 = pk[6], p7 = pk[7];

    // Zero pad rows (written once) + static rin boundary rows.
    if (tid < 64) {
        bndU[0][0][l] = 0.f; bndU[1][0][l] = 0.f;
        bndD[0][8][l] = 0.f; bndD[1][8][l] = 0.f;
        rbU[0][l] = 0.f;     rbD[8][l] = 0.f;
    }
    rbU[w + 1][l] = rik[7];
    rbD[w][l]     = rik[0];
    __syncthreads();
    const float rinU_b = rbU[w][l];
    const float rinD_b = rbD[w + 1][l];

    // Folded per-direction constants aX = rin(neighbor X) - rout.
    // Out-of-grid terms = -rout <= 0 never win (v>=0 monotone, relu >= 0,
    // DPP zero-fill at wave edges, zero pad rows vertically).
    const float aU0 = rinU_b - rok[0], aU1 = rik[0] - rok[1], aU2 = rik[1] - rok[2], aU3 = rik[2] - rok[3];
    const float aU4 = rik[3] - rok[4], aU5 = rik[4] - rok[5], aU6 = rik[5] - rok[6], aU7 = rik[6] - rok[7];
    const float aD0 = rik[1] - rok[0], aD1 = rik[2] - rok[1], aD2 = rik[3] - rok[2], aD3 = rik[4] - rok[3];
    const float aD4 = rik[5] - rok[4], aD5 = rik[6] - rok[5], aD6 = rik[7] - rok[6], aD7 = rinD_b - rok[7];
    const float aL0 = shr1(rik[0]) - rok[0], aL1 = shr1(rik[1]) - rok[1], aL2 = shr1(rik[2]) - rok[2], aL3 = shr1(rik[3]) - rok[3];
    const float aL4 = shr1(rik[4]) - rok[4], aL5 = shr1(rik[5]) - rok[5], aL6 = shr1(rik[6]) - rok[6], aL7 = shr1(rik[7]) - rok[7];
    const float aR0 = shl1(rik[0]) - rok[0], aR1 = shl1(rik[1]) - rok[1], aR2 = shl1(rik[2]) - rok[2], aR3 = shl1(rik[3]) - rok[3];
    const float aR4 = shl1(rik[4]) - rok[4], aR5 = shl1(rik[5]) - rok[5], aR6 = shl1(rik[6]) - rok[6], aR7 = shl1(rik[7]) - rok[7];

    // Iter 0 peeled (v == 0): v = max(0, aU, aD, aL, aR).
    float v0 = fmaxf(max3(aU0, aD0, aL0), fmaxf(aR0, 0.f));
    float v1 = fmaxf(max3(aU1, aD1, aL1), fmaxf(aR1, 0.f));
    float v2 = fmaxf(max3(aU2, aD2, aL2), fmaxf(aR2, 0.f));
    float v3 = fmaxf(max3(aU3, aD3, aL3), fmaxf(aR3, 0.f));
    float v4 = fmaxf(max3(aU4, aD4, aL4), fmaxf(aR4, 0.f));
    float v5 = fmaxf(max3(aU5, aD5, aL5), fmaxf(aR5, 0.f));
    float v6 = fmaxf(max3(aU6, aD6, aL6), fmaxf(aR6, 0.f));
    float v7 = fmaxf(max3(aU7, aD7, aL7), fmaxf(aR7, 0.f));
    bndU[0][w + 1][l] = v7;
    bndD[0][w][l]     = v0;

    // Iters 1..9, fully unrolled; Jacobi via SSA names.
    #pragma unroll
    for (int it = 1; it < K_ITERS; ++it) {
        const int rd = (it - 1) & 1, wr = it & 1;
        __syncthreads();
        const float vU_b = bndU[rd][w][l];
        const float vD_b = bndD[rd][w + 1][l];

        float vL, vR, m;
        vL = shr1(v7); vR = shl1(v7);
        m = max3(fmaf(p7, v6, aU7), fmaf(p7, vD_b, aD7), fmaf(p7, vL, aL7));
        const float nv7 = max3(m, fmaf(p7, vR, aR7), v7);
        bndU[wr][w + 1][l] = nv7;

        vL = shr1(v0); vR = shl1(v0);
        m = max3(fmaf(p0, vU_b, aU0), fmaf(p0, v1, aD0), fmaf(p0, vL, aL0));
        const float nv0 = max3(m, fmaf(p0, vR, aR0), v0);
        bndD[wr][w][l] = nv0;

        vL = shr1(v1); vR = shl1(v1);
        m = max3(fmaf(p1, v0, aU1), fmaf(p1, v2, aD1), fmaf(p1, vL, aL1));
        const float nv1 = max3(m, fmaf(p1, vR, aR1), v1);

        vL = shr1(v2); vR = shl1(v2);
        m = max3(fmaf(p2, v1, aU2), fmaf(p2, v3, aD2), fmaf(p2, vL, aL2));
        const float nv2 = max3(m, fmaf(p2, vR, aR2), v2);

        vL = shr1(v3); vR = shl1(v3);
        m = max3(fmaf(p3, v2, aU3), fmaf(p3, v4, aD3), fmaf(p3, vL, aL3));
        const float nv3 = max3(m, fmaf(p3, vR, aR3), v3);

        vL = shr1(v4); vR = shl1(v4);
        m = max3(fmaf(p4, v3, aU4), fmaf(p4, v5, aD4), fmaf(p4, vL, aL4));
        const float nv4 = max3(m, fmaf(p4, vR, aR4), v4);

        vL = shr1(v5); vR = shl1(v5);
        m = max3(fmaf(p5, v4, aU5), fmaf(p5, v6, aD5), fmaf(p5, vL, aL5));
        const float nv5 = max3(m, fmaf(p5, vR, aR5), v5);

        vL = shr1(v6); vR = shl1(v6);
        m = max3(fmaf(p6, v5, aU6), fmaf(p6, v7, aD6), fmaf(p6, vL, aL6));
        const float nv6 = max3(m, fmaf(p6, vR, aR6), v6);

        v0 = nv0; v1 = nv1; v2 = nv2; v3 = nv3;
        v4 = nv4; v5 = nv5; v6 = nv6; v7 = nv7;
    }

    v_s[(8 * w + 0) * 64 + l] = v0;
    v_s[(8 * w + 1) * 64 + l] = v1;
    v_s[(8 * w + 2) * 64 + l] = v2;
    v_s[(8 * w + 3) * 64 + l] = v3;
    v_s[(8 * w + 4) * 64 + l] = v4;
    v_s[(8 * w + 5) * 64 + l] = v5;
    v_s[(8 * w + 6) * 64 + l] = v6;
    v_s[(8 * w + 7) * 64 + l] = v7;
    __syncthreads();

    // ---- Gather: 36 features into LDS ----
    if (tid < 36) {
        const int ap = agent_pos;
        const int ar = ap >> 6, ac = ap & 63;
        const int g  = tid / 9, o = tid % 9;
        const int rr = ar + o / 3 - 1;
        const int cc = ac + o % 3 - 1;
        float val = 0.f;
        if (rr >= 0 && rr < 64 && cc >= 0 && cc < 64) {
            const int cell = rr * 64 + cc;
            if      (g == 0) val = 1.f - ob[cell * 3 + 0];
            else if (g == 1) val = ob[cell * 3 + 1];
            else if (g == 2) val = ob[cell * 3 + 2];
            else             val = v_s[cell];
        }
        f_s[tid] = val;
    }
    __syncthreads();

    // ---- MLP phase 1: h1 = f @ W1 + b1 (2-way K-split: h x 18 rows) ----
    {
        const int h = tid >> 8;        // 0/1
        const int c = tid & 255;
        float a = 0.f;
        #pragma unroll
        for (int m = 0; m < 18; ++m) {
            const int i = 18 * h + m;
            a = fmaf(f_s[i], W1[i * 256 + c], a);
        }
        part_s[h][c] = a;
    }
    __syncthreads();
    if (tid < 256) h1_s[tid] = b1[tid] + part_s[0][tid] + part_s[1][tid];
    __syncthreads();

    // ---- MLP phase 2: h2 = h1 @ W2 + b2 (2-way K-split: h x 128 rows) ----
    {
        const int h = tid >> 8;        // 0/1
        const int c = tid & 255;
        float a = 0.f;
        #pragma unroll
        for (int m4 = 0; m4 < 32; ++m4) {
            const int i = 128 * h + m4 * 4;
            const float4 hv = *reinterpret_cast<const float4*>(&h1_s[i]); // bcast
            a = fmaf(hv.x, W2[(i + 0) * 256 + c], a);
            a = fmaf(hv.y, W2[(i + 1) * 256 + c], a);
            a = fmaf(hv.z, W2[(i + 2) * 256 + c], a);
            a = fmaf(hv.w, W2[(i + 3) * 256 + c], a);
        }
        part_s[h][c] = a;
    }
    __syncthreads();
    if (tid < 256) h2_s[tid] = b2[tid] + part_s[0][tid] + part_s[1][tid];
    __syncthreads();

    // ---- MLP phase 3: logits (40 threads: 5 logits x 8 chunks of 32) ----
    if (tid < 40) {
        const int j  = tid % 5;
        const int ch = tid / 5;        // 0..7
        float acc = 0.f;
        #pragma unroll
        for (int m = 0; m < 32; ++m) {
            const int i = ch * 32 + m;
            acc = fmaf(h2_s[i], Wl[i * 5 + j], acc);
        }
        red[ch][j] = acc;
    }
    __syncthreads();
    if (tid < 5) {
        float o = bl[tid];
        #pragma unroll
        for (int ch = 0; ch < 8; ++ch) o += red[ch][tid];
        out[b * 5 + tid] = o;
    }
}

extern "C" void kernel_launch(void* const* d_in, const int* in_sizes, int n_in,
                              void* d_out, int out_size, void* d_ws, size_t ws_size,
                              hipStream_t stream) {
    const float* obs   = (const float*)d_in[0];
    const float* W_phi = (const float*)d_in[1];
    const float* b_phi = (const float*)d_in[2];
    const float* W1    = (const float*)d_in[3];
    const float* b1    = (const float*)d_in[4];
    const float* W2    = (const float*)d_in[5];
    const float* b2    = (const float*)d_in[6];
    const float* Wl    = (const float*)d_in[7];
    const float* bl    = (const float*)d_in[8];
    float* out = (float*)d_out;

    vin_fused_kernel<<<dim3(1024), dim3(512), 0, stream>>>(
        obs, W_phi, b_phi, W1, b1, W2, b2, Wl, bl, out);
}